// Round 5
// baseline (390.275 us; speedup 1.0000x reference)
//
#include <hip/hip_runtime.h>

#define EPS 1e-5f

typedef __attribute__((ext_vector_type(8))) short short8v;
typedef __attribute__((ext_vector_type(4))) float f32x4;

__device__ __forceinline__ unsigned short f2bf(float f) {
    unsigned u = __builtin_bit_cast(unsigned, f);
    u += 0x7fffu + ((u >> 16) & 1u);
    return (unsigned short)(u >> 16);
}
__device__ __forceinline__ float bf2f(unsigned short h) {
    return __builtin_bit_cast(float, (unsigned)h << 16);
}

// ---------------- zero workspace (float4) ----------------
__global__ __launch_bounds__(256) void zero_kernel(float* __restrict__ p, long n) {
    long i = (long)blockIdx.x * blockDim.x + threadIdx.x;
    long stride = (long)gridDim.x * blockDim.x;
    long n4 = n >> 2;
    float4* p4 = (float4*)p;
    for (long k = i; k < n4; k += stride) p4[k] = make_float4(0.f, 0.f, 0.f, 0.f);
    for (long k = (n4 << 2) + i; k < n; k += stride) p[k] = 0.f;
}

// ---------------- convert x_h (fp32) -> xbf (bf16), 8 elems/thread ----------------
__global__ __launch_bounds__(256) void xconv_kernel(const float* __restrict__ x,
                                                    unsigned short* __restrict__ xbf, long n8) {
    long i = (long)blockIdx.x * blockDim.x + threadIdx.x;
    long stride = (long)gridDim.x * blockDim.x;
    const float4* x4 = (const float4*)x;
    for (long k = i; k < n8; k += stride) {
        float4 a = x4[2 * k], b = x4[2 * k + 1];
        short8v v;
        v[0] = (short)f2bf(a.x); v[1] = (short)f2bf(a.y);
        v[2] = (short)f2bf(a.z); v[3] = (short)f2bf(a.w);
        v[4] = (short)f2bf(b.x); v[5] = (short)f2bf(b.y);
        v[6] = (short)f2bf(b.z); v[7] = (short)f2bf(b.w);
        ((short8v*)xbf)[k] = v;
    }
}

// ---------------- edge stage (MFMA, bf16 x-gather, pk_bf16 atomics) ----------------
// One wave per 64-edge tile. A-frag x-half is a single 16B load from the bf16 copy
// (4 q-lanes cover one 64B line per row -> ~4x fewer gather transactions than fp32).
__global__ __launch_bounds__(256) void edge_kernel(
    const unsigned short* __restrict__ xbf, const int* __restrict__ eidx,
    const float* __restrict__ eattr,
    const float* __restrict__ W1, const float* __restrict__ b1,
    const float* __restrict__ g1, const float* __restrict__ be1,
    unsigned short* __restrict__ summed, float* __restrict__ cnt,
    int E, int N)
{
    const int lane = threadIdx.x & 63;
    const int wid  = threadIdx.x >> 6;
    const int c = lane & 15;
    const int q = lane >> 4;

    // B fragments: W1[k][n] fp32 row-major [128][64]; lane holds k=ks*32+q*8+j, n=nt*16+c.
    short8v w1f[4][4];
    #pragma unroll
    for (int ks = 0; ks < 4; ++ks) {
        #pragma unroll
        for (int nt = 0; nt < 4; ++nt) {
            int k0 = ks * 32 + q * 8;
            int n  = nt * 16 + c;
            short8v f;
            #pragma unroll
            for (int j = 0; j < 8; ++j) f[j] = (short)f2bf(W1[(k0 + j) * 64 + n]);
            w1f[ks][nt] = f;
        }
    }
    float b1v[4], g1v[4], bev[4];
    #pragma unroll
    for (int nt = 0; nt < 4; ++nt) {
        b1v[nt] = b1[nt * 16 + c];
        g1v[nt] = g1[nt * 16 + c];
        bev[nt] = be1[nt * 16 + c];
    }

    for (long e0 = (long)blockIdx.x * 256 + wid * 64; e0 < E; e0 += (long)gridDim.x * 256) {
        // per-edge count atomic (one lane per edge, coalesced eidx load)
        {
            long el = e0 + lane;
            if (el < E) atomicAdd(&cnt[eidx[E + el]], 1.f);
        }

        #pragma unroll
        for (int mt = 0; mt < 4; ++mt) {
            long er = e0 + mt * 16 + c;
            long ec = (er < E) ? er : (E - 1);
            int src = eidx[ec];
            const unsigned short* xp = xbf + (long)src * 64;
            const float* ep = eattr + ec * 64;

            f32x4 acc[4];
            #pragma unroll
            for (int nt = 0; nt < 4; ++nt) acc[nt] = (f32x4){0.f, 0.f, 0.f, 0.f};

            // ks 0..1: x half, direct bf16 fragment load (16B)
            #pragma unroll
            for (int ks = 0; ks < 2; ++ks) {
                short8v a = *(const short8v*)(xp + ks * 32 + q * 8);
                #pragma unroll
                for (int nt = 0; nt < 4; ++nt)
                    acc[nt] = __builtin_amdgcn_mfma_f32_16x16x32_bf16(
                        a, w1f[ks][nt], acc[nt], 0, 0, 0);
            }
            // ks 2..3: eattr half, fp32 load + convert
            #pragma unroll
            for (int ks = 2; ks < 4; ++ks) {
                int k0 = (ks - 2) * 32 + q * 8;
                float4 lo = *(const float4*)(ep + k0);
                float4 hi = *(const float4*)(ep + k0 + 4);
                short8v a;
                a[0] = (short)f2bf(lo.x); a[1] = (short)f2bf(lo.y);
                a[2] = (short)f2bf(lo.z); a[3] = (short)f2bf(lo.w);
                a[4] = (short)f2bf(hi.x); a[5] = (short)f2bf(hi.y);
                a[6] = (short)f2bf(hi.z); a[7] = (short)f2bf(hi.w);
                #pragma unroll
                for (int nt = 0; nt < 4; ++nt)
                    acc[nt] = __builtin_amdgcn_mfma_f32_16x16x32_bf16(
                        a, w1f[ks][nt], acc[nt], 0, 0, 0);
            }

            // epilogue: bias + relu + LayerNorm (row = edge) + packed-bf16 atomic scatter
            float s1[4] = {0, 0, 0, 0}, s2[4] = {0, 0, 0, 0};
            #pragma unroll
            for (int nt = 0; nt < 4; ++nt) {
                #pragma unroll
                for (int r = 0; r < 4; ++r) {
                    float f = fmaxf(acc[nt][r] + b1v[nt], 0.f);
                    acc[nt][r] = f;
                    s1[r] += f; s2[r] += f * f;
                }
            }
            #pragma unroll
            for (int m = 1; m <= 8; m <<= 1) {
                #pragma unroll
                for (int r = 0; r < 4; ++r) {
                    s1[r] += __shfl_xor(s1[r], m);
                    s2[r] += __shfl_xor(s2[r], m);
                }
            }
            float mu[4], rs[4]; int dst[4];
            #pragma unroll
            for (int r = 0; r < 4; ++r) {
                mu[r] = s1[r] * (1.f / 64.f);
                float var = s2[r] * (1.f / 64.f) - mu[r] * mu[r];
                rs[r] = rsqrtf(var + EPS);
                long er2 = e0 + mt * 16 + q * 4 + r;
                dst[r] = (er2 < E) ? eidx[E + er2] : -1;
            }
            #pragma unroll
            for (int nt = 0; nt < 4; ++nt) {
                #pragma unroll
                for (int r = 0; r < 4; ++r) {
                    float outv = (acc[nt][r] - mu[r]) * rs[r] * g1v[nt] + bev[nt];
                    float nb = __shfl_xor(outv, 1);
                    if (dst[r] >= 0 && !(c & 1)) {
                        unsigned pk = (unsigned)f2bf(outv) | ((unsigned)f2bf(nb) << 16);
                        unsigned long long a64 = (unsigned long long)
                            (summed + (long)dst[r] * 64 + nt * 16 + c);
                        asm volatile("global_atomic_pk_add_bf16 %0, %1, off"
                                     :: "v"(a64), "v"(pk) : "memory");
                    }
                }
            }
        }
    }
}

// ---------------- node stage (MFMA, unchanged) ----------------
__global__ __launch_bounds__(256) void node_kernel(
    const float* __restrict__ x_h, const float* __restrict__ u,
    const float* __restrict__ W2, const float* __restrict__ b2,
    const float* __restrict__ g2, const float* __restrict__ be2,
    const float* __restrict__ W3, const float* __restrict__ b3,
    const float* __restrict__ g3, const float* __restrict__ be3,
    const unsigned short* __restrict__ summed, const float* __restrict__ cnt,
    float* __restrict__ out, int N)
{
    __shared__ unsigned short sh[4][64][72];

    const int lane = threadIdx.x & 63;
    const int wid  = threadIdx.x >> 6;
    const int c = lane & 15;
    const int q = lane >> 4;
    const float u0 = u[0];

    short8v w2f[4][4], w3f[2][4];
    #pragma unroll
    for (int ks = 0; ks < 4; ++ks)
        #pragma unroll
        for (int nt = 0; nt < 4; ++nt) {
            int k0 = ks * 32 + q * 8;
            int n  = nt * 16 + c;
            short8v f;
            #pragma unroll
            for (int j = 0; j < 8; ++j) f[j] = (short)f2bf(W2[(k0 + j) * 64 + n]);
            w2f[ks][nt] = f;
        }
    #pragma unroll
    for (int ks = 0; ks < 2; ++ks)
        #pragma unroll
        for (int nt = 0; nt < 4; ++nt) {
            int k0 = ks * 32 + q * 8;
            int n  = nt * 16 + c;
            short8v f;
            #pragma unroll
            for (int j = 0; j < 8; ++j) f[j] = (short)f2bf(W3[(k0 + j) * 64 + n]);
            w3f[ks][nt] = f;
        }

    float b2p[4], g2v[4], be2v[4], b3v[4], g3v[4], be3v[4];
    #pragma unroll
    for (int nt = 0; nt < 4; ++nt) {
        int n = nt * 16 + c;
        b2p[nt] = b2[n] + u0 * W2[128 * 64 + n];
        g2v[nt] = g2[n]; be2v[nt] = be2[n];
        b3v[nt] = b3[n]; g3v[nt] = g3[n]; be3v[nt] = be3[n];
    }

    const long n0 = ((long)blockIdx.x * 4 + wid) * 64;
    if (n0 >= N) return;

    #pragma unroll
    for (int mt = 0; mt < 4; ++mt) {
        long nr = n0 + mt * 16 + c;
        long nc = (nr < N) ? nr : (N - 1);
        const float* xp = x_h + nc * 64;
        const unsigned short* sp = summed + nc * 64;
        float inv = 1.f / fmaxf(cnt[nc], 1.f);

        f32x4 acc[4];
        #pragma unroll
        for (int nt = 0; nt < 4; ++nt) acc[nt] = (f32x4){0.f, 0.f, 0.f, 0.f};

        #pragma unroll
        for (int ks = 0; ks < 4; ++ks) {
            int k0 = ks * 32 + q * 8;
            short8v a;
            if (ks < 2) {
                float4 lo = *(const float4*)(xp + k0);
                float4 hi = *(const float4*)(xp + k0 + 4);
                a[0] = (short)f2bf(lo.x); a[1] = (short)f2bf(lo.y);
                a[2] = (short)f2bf(lo.z); a[3] = (short)f2bf(lo.w);
                a[4] = (short)f2bf(hi.x); a[5] = (short)f2bf(hi.y);
                a[6] = (short)f2bf(hi.z); a[7] = (short)f2bf(hi.w);
            } else {
                short8v raw = *(const short8v*)(sp + (k0 - 64));
                #pragma unroll
                for (int j = 0; j < 8; ++j)
                    a[j] = (short)f2bf(bf2f((unsigned short)raw[j]) * inv);
            }
            #pragma unroll
            for (int nt = 0; nt < 4; ++nt)
                acc[nt] = __builtin_amdgcn_mfma_f32_16x16x32_bf16(a, w2f[ks][nt], acc[nt], 0, 0, 0);
        }

        float s1[4] = {0, 0, 0, 0}, s2[4] = {0, 0, 0, 0};
        #pragma unroll
        for (int nt = 0; nt < 4; ++nt)
            #pragma unroll
            for (int r = 0; r < 4; ++r) {
                float f = fmaxf(acc[nt][r] + b2p[nt], 0.f);
                acc[nt][r] = f;
                s1[r] += f; s2[r] += f * f;
            }
        #pragma unroll
        for (int m = 1; m <= 8; m <<= 1)
            #pragma unroll
            for (int r = 0; r < 4; ++r) {
                s1[r] += __shfl_xor(s1[r], m);
                s2[r] += __shfl_xor(s2[r], m);
            }
        #pragma unroll
        for (int r = 0; r < 4; ++r) {
            float mu = s1[r] * (1.f / 64.f);
            float var = s2[r] * (1.f / 64.f) - mu * mu;
            float rs = rsqrtf(var + EPS);
            #pragma unroll
            for (int nt = 0; nt < 4; ++nt) {
                float h2 = (acc[nt][r] - mu) * rs * g2v[nt] + be2v[nt];
                sh[wid][mt * 16 + q * 4 + r][nt * 16 + c] = f2bf(h2);
            }
        }
    }

    #pragma unroll
    for (int mt = 0; mt < 4; ++mt) {
        f32x4 acc[4];
        #pragma unroll
        for (int nt = 0; nt < 4; ++nt) acc[nt] = (f32x4){0.f, 0.f, 0.f, 0.f};

        #pragma unroll
        for (int ks = 0; ks < 2; ++ks) {
            short8v a = *(const short8v*)&sh[wid][mt * 16 + c][ks * 32 + q * 8];
            #pragma unroll
            for (int nt = 0; nt < 4; ++nt)
                acc[nt] = __builtin_amdgcn_mfma_f32_16x16x32_bf16(a, w3f[ks][nt], acc[nt], 0, 0, 0);
        }

        float s1[4] = {0, 0, 0, 0}, s2[4] = {0, 0, 0, 0};
        #pragma unroll
        for (int nt = 0; nt < 4; ++nt)
            #pragma unroll
            for (int r = 0; r < 4; ++r) {
                float f = acc[nt][r] + b3v[nt];
                acc[nt][r] = f;
                s1[r] += f; s2[r] += f * f;
            }
        #pragma unroll
        for (int m = 1; m <= 8; m <<= 1)
            #pragma unroll
            for (int r = 0; r < 4; ++r) {
                s1[r] += __shfl_xor(s1[r], m);
                s2[r] += __shfl_xor(s2[r], m);
            }
        #pragma unroll
        for (int r = 0; r < 4; ++r) {
            float mu = s1[r] * (1.f / 64.f);
            float var = s2[r] * (1.f / 64.f) - mu * mu;
            float rs = rsqrtf(var + EPS);
            long node = n0 + mt * 16 + q * 4 + r;
            if (node < N) {
                #pragma unroll
                for (int nt = 0; nt < 4; ++nt) {
                    long off = node * 64 + nt * 16 + c;
                    float h3 = (acc[nt][r] - mu) * rs * g3v[nt] + be3v[nt];
                    out[off] = h3 + x_h[off];
                }
            }
        }
    }
}

extern "C" void kernel_launch(void* const* d_in, const int* in_sizes, int n_in,
                              void* d_out, int out_size, void* d_ws, size_t ws_size,
                              hipStream_t stream)
{
    const float* x_h   = (const float*)d_in[0];
    const int*   eidx  = (const int*)  d_in[1];
    const float* eattr = (const float*)d_in[2];
    const float* u     = (const float*)d_in[3];
    // d_in[4] = batch (all zeros, B=1) -> unused
    const float* W1  = (const float*)d_in[5];
    const float* b1  = (const float*)d_in[6];
    const float* g1  = (const float*)d_in[7];
    const float* be1 = (const float*)d_in[8];
    const float* W2  = (const float*)d_in[9];
    const float* b2  = (const float*)d_in[10];
    const float* g2  = (const float*)d_in[11];
    const float* be2 = (const float*)d_in[12];
    const float* W3  = (const float*)d_in[13];
    const float* b3  = (const float*)d_in[14];
    const float* g3  = (const float*)d_in[15];
    const float* be3 = (const float*)d_in[16];

    const int N = in_sizes[0] / 64;
    const int E = in_sizes[1] / 2;

    // workspace layout: xbf [N*64 bf16 = N*128B] | summed [N*64 bf16 = N*128B] | cnt [N f32]
    unsigned short* xbf    = (unsigned short*)d_ws;
    unsigned short* summed = (unsigned short*)((char*)d_ws + (size_t)N * 128);
    float*          cnt    = (float*)((char*)d_ws + (size_t)N * 256);

    // zero summed+cnt (N*32 + N floats), convert x -> bf16
    zero_kernel<<<1024, 256, 0, stream>>>((float*)summed, (long)N * 33);
    xconv_kernel<<<512, 256, 0, stream>>>(x_h, xbf, (long)N * 8);

    // tail-balanced grid: 18750 tiles / 3 per wave / 4 waves per block
    int tiles  = (E + 63) / 64;
    int eblocks = (tiles + 11) / 12;
    edge_kernel<<<eblocks, 256, 0, stream>>>(xbf, eidx, eattr, W1, b1, g1, be1,
                                             summed, cnt, E, N);

    int nblocks = (N + 255) / 256;
    node_kernel<<<nblocks, 256, 0, stream>>>(x_h, u, W2, b2, g2, be2, W3, b3, g3, be3,
                                             summed, cnt, (float*)d_out, N);
}